// Round 17
// baseline (197.397 us; speedup 1.0000x reference)
//
#include <hip/hip_runtime.h>
#include <stdint.h>

// GraphSAGE 2-layer, MI355X. Round 16: gemm2 fused into agg1.
// Each agg1 bucket owns h rows [nb,nb+nn) == exactly the rows gemm2's tile
// needs. Epilogue writes h to LDS hs[112][136] (global h eliminated: 25.6MB
// write + 25.6MB read saved), then 7 waves MFMA hs x Wt2 -> z2p|r2 in-block.
// ebuf aliases hs (dead after sort placement). agg2 unchanged (reads all
// buckets' z2p -> must stay a separate kernel).
// Rest = R15 (183.8us): k_fused1 = part1 || gemm1, part2 4096-tiles CAPB=96,
// sort-once CSR persisted for agg2.

typedef unsigned int uint32;
typedef unsigned short u16;
typedef __bf16 bf16x8 __attribute__((ext_vector_type(8)));
typedef float  f32x4  __attribute__((ext_vector_type(4)));
typedef unsigned short u16x8 __attribute__((ext_vector_type(8)));

#define CAPB 96     // part2 per-sub-bucket LDS staging (4096-edge tiles)
#define MAXE 2592   // agg LDS edge buffer (>= cap2)
#define MAXN 104    // agg max nodes per bucket
#define RSST 112    // rsg row stride (ints)

__device__ __forceinline__ float bf2f(u16 u) {
    union { uint32 i; float f; } v; v.i = ((uint32)u) << 16; return v.f;
}
__device__ __forceinline__ u16 f2bf(float f) {
    union { float f; uint32 i; } v; v.f = f;
    uint32 i = v.i;
    uint32 r = (i + 0x7FFFu + ((i >> 16) & 1u)) >> 16;  // RNE
    return (u16)r;
}

// ---------------- weight prep: transpose + bf16 + gcur inits ----------------
__global__ void k_prep(const float* __restrict__ W1l, const float* __restrict__ W1r,
                       const float* __restrict__ W2l, const float* __restrict__ W2r,
                       u16* __restrict__ Wt1, u16* __restrict__ Wt2,
                       int* __restrict__ gcur1, int cap1,
                       int* __restrict__ gcur2, int cap2) {
    if (blockIdx.x == 0 && threadIdx.x < 8) gcur1[threadIdx.x] = threadIdx.x * cap1;
    if (blockIdx.x < 4) {
        int idx = blockIdx.x * 256 + threadIdx.x;
        gcur2[idx] = idx * cap2;
    }
    if (blockIdx.x < 128) {
        int idx = blockIdx.x * 256 + threadIdx.x;
        int c = idx >> 7, k = idx & 127;
        float v = (c < 128) ? W1l[k * 128 + c] : W1r[k * 128 + (c - 128)];
        Wt1[idx] = f2bf(v);
    } else {
        int idx = (blockIdx.x - 128) * 256 + threadIdx.x;  // 96*128 total
        int c = idx >> 7, k = idx & 127;
        const float* W = (c < 48) ? W2l : W2r;
        int cc = (c < 48) ? c : c - 48;
        float v = (cc < 40) ? W[k * 40 + cc] : 0.f;
        Wt2[idx] = f2bf(v);
    }
}

// ---------------- fused: part1 (blocks < nt1) | gemm1 (blocks >= nt1) --------
__global__ __launch_bounds__(512) void k_fused1(
        const int* __restrict__ src, const int* __restrict__ dst,
        uint32* __restrict__ part, int* __restrict__ gcur,
        int E, int sw, uint32 magic, int cap, int nt1,
        const float* __restrict__ x, const u16* __restrict__ Wt,
        u16* __restrict__ z1, u16* __restrict__ r1, int N) {
    int tid = threadIdx.x;
    if ((int)blockIdx.x < nt1) {
        // ---------------- part1 tile ----------------
        __shared__ uint32 buf[2048];
        __shared__ int cnt8[8][8];
        __shared__ int base8[8][8];
        __shared__ int bstart[8], bn[8], gbase[8];
        int rep = tid & 7;
        int tile = blockIdx.x;
        if (tid < 64) cnt8[tid >> 3][tid & 7] = 0;
        __syncthreads();
        int e0 = (tile << 11) + tid * 4;
        int bk[4]; uint32 pk[4]; int nv = 0;
        if (e0 + 3 < E) {
            int4 d4 = *(const int4*)(dst + e0);
            int4 s4 = *(const int4*)(src + e0);
            int dd[4] = {d4.x, d4.y, d4.z, d4.w};
            int ss[4] = {s4.x, s4.y, s4.z, s4.w};
            nv = 4;
#pragma unroll
            for (int k = 0; k < 4; ++k) {
                bk[k] = (int)(((unsigned long long)(uint32)dd[k] * magic) >> 32);
                pk[k] = ((uint32)ss[k] << 14) | (uint32)(dd[k] - bk[k] * sw);
            }
        } else {
            for (int e = e0; e < E && e < e0 + 4; ++e) {
                int d = dst[e];
                int b = (int)(((unsigned long long)(uint32)d * magic) >> 32);
                bk[nv] = b;
                pk[nv] = ((uint32)src[e] << 14) | (uint32)(d - b * sw);
                ++nv;
            }
        }
        for (int k = 0; k < nv; ++k) atomicAdd(&cnt8[bk[k]][rep], 1);
        __syncthreads();
        if (tid == 0) {
            int run = 0;
            for (int b = 0; b < 8; ++b) {
                bstart[b] = run; int t0 = run;
                for (int r = 0; r < 8; ++r) { base8[b][r] = run; run += cnt8[b][r]; }
                bn[b] = run - t0;
            }
        }
        __syncthreads();
        if (tid < 64) cnt8[tid >> 3][tid & 7] = base8[tid >> 3][tid & 7];
        __syncthreads();
        for (int k = 0; k < nv; ++k) {
            int pos = atomicAdd(&cnt8[bk[k]][rep], 1);
            buf[pos] = pk[k];
        }
        if (tid < 8 && bn[tid] > 0)
            gbase[tid] = atomicAdd(&gcur[tid], bn[tid]);
        __syncthreads();
#pragma unroll
        for (int b = 0; b < 8; ++b) {
            int n = bn[b];
            if (n == 0) continue;
            int gb = gbase[b], bs = bstart[b];
            int lim = (b + 1) * cap;
            for (int i = tid; i < n; i += 512) {
                int p = gb + i;
                if (p < lim) part[p] = buf[bs + i];
            }
        }
    } else {
        // ---------------- gemm1 tile ----------------
        __shared__ u16 xs[128][136];
        int rbase = ((int)blockIdx.x - nt1) * 128;
#pragma unroll
        for (int i = 0; i < 8; ++i) {       // 4096 float4 chunks, coalesced
            int fi = tid + i * 512;
            int row = fi >> 5, c4 = fi & 31;
            int grow = rbase + row;
            grow = grow < N ? grow : N - 1;
            float4 v = *(const float4*)(x + ((size_t)grow << 7) + c4 * 4);
            ushort4 w4;
            w4.x = f2bf(v.x); w4.y = f2bf(v.y); w4.z = f2bf(v.z); w4.w = f2bf(v.w);
            *(ushort4*)&xs[row][c4 * 4] = w4;
        }

        int lane = tid & 63;
        int w    = tid >> 6;
        int l15 = lane & 15, g = lane >> 4;
        int rloc = (w >> 2) * 64;
        int cbase = (w & 3) * 64;

        bf16x8 Bf[4][4];
#pragma unroll
        for (int c = 0; c < 4; ++c)
#pragma unroll
            for (int ks = 0; ks < 4; ++ks)
                Bf[c][ks] = *(const bf16x8*)(Wt + (((size_t)(cbase + c * 16 + l15)) << 7)
                                                + ks * 32 + g * 8);

        f32x4 acc[4][4];
        f32x4 z4 = {0.f, 0.f, 0.f, 0.f};
#pragma unroll
        for (int r = 0; r < 4; ++r)
#pragma unroll
            for (int c = 0; c < 4; ++c) acc[r][c] = z4;

        __syncthreads();

#pragma unroll
        for (int ks = 0; ks < 4; ++ks) {
            bf16x8 Af[4];
#pragma unroll
            for (int r = 0; r < 4; ++r)
                Af[r] = *(const bf16x8*)&xs[rloc + r * 16 + l15][ks * 32 + g * 8];
#pragma unroll
            for (int r = 0; r < 4; ++r)
#pragma unroll
                for (int c = 0; c < 4; ++c)
                    acc[r][c] = __builtin_amdgcn_mfma_f32_16x16x32_bf16(
                                    Af[r], Bf[c][ks], acc[r][c], 0, 0, 0);
        }

        // C/D layout: col = lane&15, row = (lane>>4)*4 + j
#pragma unroll
        for (int r = 0; r < 4; ++r) {
#pragma unroll
            for (int c = 0; c < 4; ++c) {
                int col = cbase + c * 16 + l15;
                u16* out = (col < 128) ? z1 : r1;
                int cc = col & 127;
#pragma unroll
                for (int j = 0; j < 4; ++j) {
                    int row = rbase + rloc + r * 16 + g * 4 + j;
                    if (row < N) out[((size_t)row << 7) + cc] = f2bf(acc[r][c][j]);
                }
            }
        }
    }
}

// ---------------- pass 2: slice -> 128 sub-buckets (4096-edge tiles) ---------
__global__ __launch_bounds__(256) void k_part2(const uint32* __restrict__ part1,
        const int* __restrict__ gcur1, uint32* __restrict__ part2,
        int* __restrict__ gcur2, int cap1, int cap2, int sw2, uint32 magic2) {
    __shared__ uint32 buf[128][CAPB];
    __shared__ int lcnt[128], gbase[128];
    int s = blockIdx.x & 7;
    int m = gcur1[s] - s * cap1;
    const uint32* p1 = part1 + (size_t)s * cap1;
    int sbase = s * 128;
    int ntiles = (m + 4095) >> 12;
    for (int tile = blockIdx.x >> 3; tile < ntiles; tile += (gridDim.x >> 3)) {
        for (int i = threadIdx.x; i < 128; i += 256) lcnt[i] = 0;
        __syncthreads();
#pragma unroll
        for (int q = 0; q < 4; ++q) {
            int t0 = (tile << 12) + q * 1024 + threadIdx.x * 4;
            if (t0 + 3 < m) {
                uint4 v4 = *(const uint4*)(p1 + t0);
                uint32 vv[4] = {v4.x, v4.y, v4.z, v4.w};
#pragma unroll
                for (int k = 0; k < 4; ++k) {
                    uint32 dl = vv[k] & 16383u;
                    int sub = (int)(((unsigned long long)dl * magic2) >> 32);
                    uint32 pk = ((vv[k] >> 14) << 7) | (dl - (uint32)(sub * sw2));
                    int slot = atomicAdd(&lcnt[sub], 1);
                    if (slot < CAPB) buf[sub][slot] = pk;
                    else {   // rare spill: direct global append (no drops)
                        int p = atomicAdd(&gcur2[sbase + sub], 1);
                        if (p < (sbase + sub + 1) * cap2) part2[p] = pk;
                    }
                }
            } else {
                for (int idx = t0; idx < m && idx < t0 + 4; ++idx) {
                    uint32 v = p1[idx];
                    uint32 dl = v & 16383u;
                    int sub = (int)(((unsigned long long)dl * magic2) >> 32);
                    uint32 pk = ((v >> 14) << 7) | (dl - (uint32)(sub * sw2));
                    int slot = atomicAdd(&lcnt[sub], 1);
                    if (slot < CAPB) buf[sub][slot] = pk;
                    else {
                        int p = atomicAdd(&gcur2[sbase + sub], 1);
                        if (p < (sbase + sub + 1) * cap2) part2[p] = pk;
                    }
                }
            }
        }
        __syncthreads();
        if (threadIdx.x < 128) {
            int n = min(lcnt[threadIdx.x], CAPB);
            lcnt[threadIdx.x] = n;
            if (n > 0) gbase[threadIdx.x] = atomicAdd(&gcur2[sbase + threadIdx.x], n);
        }
        __syncthreads();
        int b = threadIdx.x >> 1, halfsel = threadIdx.x & 1;
        int n = lcnt[b];
        if (n > 0) {
            int gb = gbase[b];
            int lim = (sbase + b + 1) * cap2;
            for (int i = halfsel; i < n; i += 2) {
                int p = gb + i;
                if (p < lim) part2[p] = buf[b][i];
            }
        }
        __syncthreads();
    }
}

// ------- Layer-1 agg + fused Layer-2 GEMM: sort, gather, h->LDS, MFMA -------
__global__ __launch_bounds__(512) void k_agg1g2(const u16* __restrict__ z1,
        const u16* __restrict__ r1, const float* __restrict__ b1,
        uint32* __restrict__ part2, const int* __restrict__ gcur2,
        const u16* __restrict__ Wt2, u16* __restrict__ z2p, u16* __restrict__ r2,
        int* __restrict__ rsg, int N, int sw1, int sw2, int cap2) {
    __shared__ u16 hs[112][136];            // h tile; ebuf aliases this
    __shared__ uint32 esrt[MAXE];
    __shared__ int cnt[MAXN], cur[MAXN], rs[MAXN + 32];
    uint32* ebuf = (uint32*)&hs[0][0];      // MAXE*4 = 10.4KB <= 30.5KB
    int b = blockIdx.x, s = b >> 7, sub = b & 127;
    int nb = s * sw1 + sub * sw2;
    int slice_end = min((s + 1) * sw1, N);
    int nn = min(sw2, slice_end - nb);
    if (nn <= 0) return;
    int tid = threadIdx.x;
    int m2 = gcur2[b] - b * cap2;
    m2 = min(m2, min(cap2, MAXE));
    uint32* p2 = part2 + (size_t)b * cap2;

    for (int i = tid; i < m2; i += 512) ebuf[i] = p2[i];
    for (int i = tid; i < nn; i += 512) cnt[i] = 0;
    __syncthreads();
    for (int i = tid; i < m2; i += 512) atomicAdd(&cnt[ebuf[i] & 127], 1);
    __syncthreads();
    if (tid < 64) {   // wave-0 prefix scan of cnt[0..103] -> rs (exclusive)
        int c0 = (tid < nn) ? cnt[tid] : 0;
        int c1 = (64 + tid < nn) ? cnt[64 + tid] : 0;
        for (int off = 1; off < 64; off <<= 1) {
            int t0 = __shfl_up(c0, off, 64);
            int t1 = __shfl_up(c1, off, 64);
            if (tid >= off) { c0 += t0; c1 += t1; }
        }
        int tot0 = __shfl(c0, 63, 64);
        if (tid == 0) rs[0] = 0;
        rs[tid + 1] = c0;
        rs[64 + tid + 1] = tot0 + c1;
    }
    __syncthreads();
    for (int i = tid; i < nn; i += 512) cur[i] = rs[i];
    __syncthreads();
    for (int i = tid; i < m2; i += 512) {   // place srcs sorted by dst
        uint32 v = ebuf[i];
        int pos = atomicAdd(&cur[v & 127], 1);
        esrt[pos] = v >> 7;
    }
    __syncthreads();                         // ebuf dead -> hs reusable

    // persist sorted list + rowstarts for k_agg2_f (coalesced)
    for (int i = tid; i < m2; i += 512) p2[i] = esrt[i];
    for (int i = tid; i <= nn; i += 512) rsg[b * RSST + i] = rs[i];

    int lane = tid & 63, wv = tid >> 6;
    int g = lane >> 4, c = lane & 15;
    for (int node = wv; node < nn; node += 8) {
        int s0 = rs[node], s1 = rs[node + 1];
        float acc[8];
#pragma unroll
        for (int i = 0; i < 8; ++i) acc[i] = 0.f;
        int j = s0 + g;
        for (; j + 12 < s1; j += 16) {
            int sA = esrt[j], sB = esrt[j + 4];
            int sC = esrt[j + 8], sD = esrt[j + 12];
            u16x8 a = *(const u16x8*)(z1 + ((size_t)sA << 7) + c * 8);
            u16x8 bb = *(const u16x8*)(z1 + ((size_t)sB << 7) + c * 8);
            u16x8 d = *(const u16x8*)(z1 + ((size_t)sC << 7) + c * 8);
            u16x8 e = *(const u16x8*)(z1 + ((size_t)sD << 7) + c * 8);
#pragma unroll
            for (int i = 0; i < 8; ++i)
                acc[i] += (bf2f(a[i]) + bf2f(bb[i])) + (bf2f(d[i]) + bf2f(e[i]));
        }
        for (; j + 4 < s1; j += 8) {
            int sA = esrt[j], sB = esrt[j + 4];
            u16x8 a = *(const u16x8*)(z1 + ((size_t)sA << 7) + c * 8);
            u16x8 bb = *(const u16x8*)(z1 + ((size_t)sB << 7) + c * 8);
#pragma unroll
            for (int i = 0; i < 8; ++i) acc[i] += bf2f(a[i]) + bf2f(bb[i]);
        }
        if (j < s1) {
            int sA = esrt[j];
            u16x8 a = *(const u16x8*)(z1 + ((size_t)sA << 7) + c * 8);
#pragma unroll
            for (int i = 0; i < 8; ++i) acc[i] += bf2f(a[i]);
        }
#pragma unroll
        for (int i = 0; i < 8; ++i) {
            acc[i] += __shfl_xor(acc[i], 16, 64);
            acc[i] += __shfl_xor(acc[i], 32, 64);
        }
        if (g == 0) {   // h row -> LDS (global h eliminated)
            float inv = 1.0f / fmaxf((float)(s1 - s0), 1.0f);
            size_t go = ((size_t)(nb + node) << 7) + c * 8;
            u16x8 rv = *(const u16x8*)(r1 + go);
            float4 b0 = *(const float4*)(b1 + c * 8);
            float4 b4 = *(const float4*)(b1 + c * 8 + 4);
            float bbv[8] = {b0.x, b0.y, b0.z, b0.w, b4.x, b4.y, b4.z, b4.w};
            u16x8 o;
#pragma unroll
            for (int i = 0; i < 8; ++i)
                o[i] = f2bf(fmaxf(acc[i] * inv + bf2f(rv[i]) + bbv[i], 0.f));
            *(u16x8*)&hs[node][c * 8] = o;
        }
    }
    // zero-fill hs rows [nn,112) cols 0..127 (feed MFMA, outputs not stored)
    {
        int r0 = nn + (tid >> 4), cc = tid & 15;
        u16x8 z8 = {0, 0, 0, 0, 0, 0, 0, 0};
        for (int r = r0; r < 112; r += 32) *(u16x8*)&hs[r][cc * 8] = z8;
    }
    __syncthreads();

    // ---- fused gemm2: hs[nn x 128] x Wt2[96 x 128]^T -> z2p | r2 ----
    // wave w (0..6) handles rows [w*16, w*16+16); 6 col-frags x 4 ks.
    int l15 = lane & 15;
    if (wv < 7 && wv * 16 < nn) {
        f32x4 acc6[6];
        f32x4 z4 = {0.f, 0.f, 0.f, 0.f};
#pragma unroll
        for (int cf = 0; cf < 6; ++cf) acc6[cf] = z4;
#pragma unroll
        for (int ks = 0; ks < 4; ++ks) {
            bf16x8 Af = *(const bf16x8*)&hs[wv * 16 + l15][ks * 32 + g * 8];
#pragma unroll
            for (int cf = 0; cf < 6; ++cf) {
                bf16x8 Bf = *(const bf16x8*)(Wt2 + (((size_t)(cf * 16 + l15)) << 7)
                                                 + ks * 32 + g * 8);
                acc6[cf] = __builtin_amdgcn_mfma_f32_16x16x32_bf16(
                               Af, Bf, acc6[cf], 0, 0, 0);
            }
        }
        // C/D: col = l15, row = g*4 + j (local row = wv*16 + g*4 + j)
#pragma unroll
        for (int cf = 0; cf < 6; ++cf) {
#pragma unroll
            for (int j = 0; j < 4; ++j) {
                int lr = wv * 16 + g * 4 + j;
                if (lr >= nn) continue;
                int grow = nb + lr;
                if (cf < 3) {
                    int col = cf * 16 + l15;            // 0..47 -> z2p
                    z2p[((size_t)grow << 6) + col] = f2bf(acc6[cf][j]);
                } else {
                    int col = (cf - 3) * 16 + l15;      // 0..47 -> r2 (keep <40)
                    if (col < 40)
                        r2[(size_t)grow * 40 + col] = f2bf(acc6[cf][j]);
                }
            }
        }
    }
    // zero-fill z2p cols 48..63 for this bucket's rows
    for (int r = tid >> 1; r < nn; r += 256) {
        u16x8 z8 = {0, 0, 0, 0, 0, 0, 0, 0};
        *(u16x8*)(z2p + (((size_t)(nb + r)) << 6) + 48 + (tid & 1) * 8) = z8;
    }
}

// ---------------- Layer-2 agg: pre-sorted gather + log_softmax ---------------
__global__ __launch_bounds__(512) void k_agg2_f(const u16* __restrict__ z2p,
        const u16* __restrict__ r2, const float* __restrict__ b2,
        const uint32* __restrict__ part2, const int* __restrict__ gcur2,
        const int* __restrict__ rsg, float* __restrict__ out,
        int N, int sw1, int sw2, int cap2) {
    __shared__ uint32 esrt[MAXE];
    __shared__ int rs[MAXN + 1];
    int b = blockIdx.x, s = b >> 7, sub = b & 127;
    int nb = s * sw1 + sub * sw2;
    int slice_end = min((s + 1) * sw1, N);
    int nn = min(sw2, slice_end - nb);
    if (nn <= 0) return;
    int tid = threadIdx.x;
    int m2 = gcur2[b] - b * cap2;
    m2 = min(m2, min(cap2, MAXE));
    const uint32* p2 = part2 + (size_t)b * cap2;

    for (int i = tid; i < m2; i += 512) esrt[i] = p2[i];
    for (int i = tid; i <= nn; i += 512) rs[i] = rsg[b * RSST + i];
    __syncthreads();

    int lane = tid & 63, wv = tid >> 6;
    int le = lane >> 3, c = lane & 7;
    bool act = c < 5;
    for (int node = wv; node < nn; node += 8) {
        int s0 = rs[node], s1 = rs[node + 1];
        float acc[8];
#pragma unroll
        for (int i = 0; i < 8; ++i) acc[i] = 0.f;
        int j = s0 + le;
        for (; j + 8 < s1; j += 16) {
            int sA = esrt[j], sB = esrt[j + 8];
            u16x8 a = *(const u16x8*)(z2p + ((size_t)sA << 6) + c * 8);
            u16x8 bb = *(const u16x8*)(z2p + ((size_t)sB << 6) + c * 8);
#pragma unroll
            for (int i = 0; i < 8; ++i) acc[i] += bf2f(a[i]) + bf2f(bb[i]);
        }
        if (j < s1) {
            int sA = esrt[j];
            u16x8 a = *(const u16x8*)(z2p + ((size_t)sA << 6) + c * 8);
#pragma unroll
            for (int i = 0; i < 8; ++i) acc[i] += bf2f(a[i]);
        }
#pragma unroll
        for (int i = 0; i < 8; ++i) {
            acc[i] += __shfl_xor(acc[i], 8, 64);
            acc[i] += __shfl_xor(acc[i], 16, 64);
            acc[i] += __shfl_xor(acc[i], 32, 64);
        }
        if (le == 0) {   // lanes 0..7: chans c*8..c*8+7; only c<5 real (40 ch)
            float inv = 1.0f / fmaxf((float)(s1 - s0), 1.0f);
            float v[8];
            if (act) {
                u16x8 rv = *(const u16x8*)(r2 + (size_t)(nb + node) * 40 + c * 8);
                float4 b0 = *(const float4*)(b2 + c * 8);
                float4 b4 = *(const float4*)(b2 + c * 8 + 4);
                float bbv[8] = {b0.x, b0.y, b0.z, b0.w, b4.x, b4.y, b4.z, b4.w};
#pragma unroll
                for (int i = 0; i < 8; ++i) v[i] = acc[i] * inv + bf2f(rv[i]) + bbv[i];
            } else {
#pragma unroll
                for (int i = 0; i < 8; ++i) v[i] = -1e30f;
            }
            float m = v[0];
#pragma unroll
            for (int i = 1; i < 8; ++i) m = fmaxf(m, v[i]);
            m = fmaxf(m, __shfl_xor(m, 1, 64));
            m = fmaxf(m, __shfl_xor(m, 2, 64));
            m = fmaxf(m, __shfl_xor(m, 4, 64));
            float sum = 0.f;
            if (act) {
#pragma unroll
                for (int i = 0; i < 8; ++i) sum += __expf(v[i] - m);
            }
            sum += __shfl_xor(sum, 1, 64);
            sum += __shfl_xor(sum, 2, 64);
            sum += __shfl_xor(sum, 4, 64);
            float lse = __logf(sum);
            if (act) {
                float4 o0, o4;
                o0.x = v[0] - m - lse; o0.y = v[1] - m - lse;
                o0.z = v[2] - m - lse; o0.w = v[3] - m - lse;
                o4.x = v[4] - m - lse; o4.y = v[5] - m - lse;
                o4.z = v[6] - m - lse; o4.w = v[7] - m - lse;
                *(float4*)(out + (size_t)(nb + node) * 40 + c * 8) = o0;
                *(float4*)(out + (size_t)(nb + node) * 40 + c * 8 + 4) = o4;
            }
        }
    }
}

extern "C" void kernel_launch(void* const* d_in, const int* in_sizes, int n_in,
                              void* d_out, int out_size, void* d_ws, size_t ws_size,
                              hipStream_t stream) {
    const float* x   = (const float*)d_in[0];
    const int*   ei  = (const int*)d_in[1];   // [2][E] int32
    const float* W1l = (const float*)d_in[2];
    const float* W1r = (const float*)d_in[3];
    const float* b1  = (const float*)d_in[4];
    const float* W2l = (const float*)d_in[5];
    const float* W2r = (const float*)d_in[6];
    const float* b2  = (const float*)d_in[7];
    float* out = (float*)d_out;

    int N = in_sizes[0] / 128;
    int E = in_sizes[1] / 2;
    const int* esrc = ei;
    const int* edst = ei + E;

    int sw1 = (N + 7) / 8;                               // 12500 (<=16384: 14 bits)
    int sw2 = (sw1 + 127) / 128;                         // 98 (<=104: LDS bound)
    uint32 magic1 = (uint32)((((unsigned long long)1 << 32) + sw1 - 1) / sw1);
    uint32 magic2 = (uint32)((((unsigned long long)1 << 32) + sw2 - 1) / sw2);
    int cap1 = (((E >> 3) + 8192) + 3) & ~3;
    int cap2 = (((E >> 10) + 1024) + 3) & ~3;            // 2588 <= MAXE

    // workspace carve (256B aligned)
    char* p = (char*)d_ws;
    size_t off = 0;
    auto alloc = [&](size_t bytes) {
        void* q = p + off;
        off = (off + bytes + 255) & ~(size_t)255;
        return q;
    };
    int* gcur1 = (int*)alloc(64);
    int* gcur2 = (int*)alloc(1024 * 4);
    int* rsg   = (int*)alloc((size_t)1024 * RSST * 4);
    u16* Wt1 = (u16*)alloc(256 * 128 * 2);
    u16* Wt2 = (u16*)alloc(96 * 128 * 2);
    uint32* part1 = (uint32*)alloc((size_t)8 * cap1 * 4);
    uint32* part2 = (uint32*)alloc((size_t)1024 * cap2 * 4);
    u16* z1 = (u16*)alloc((size_t)N * 128 * 2);
    u16* r1 = (u16*)alloc((size_t)N * 128 * 2);
    // layer-2 buffers: z2p/r2 get their own space (z1 stays live through agg1g2)
    u16* z2p = (u16*)alloc((size_t)N * 64 * 2);
    u16* r2  = (u16*)alloc((size_t)N * 40 * 2);

    int nt1 = (E + 2047) >> 11;           // part1 tiles (2048 edges, 512 thr)
    int ng1 = (N + 127) / 128;            // gemm1 tiles

    k_prep<<<176, 256, 0, stream>>>(W1l, W1r, W2l, W2r, Wt1, Wt2,
                                    gcur1, cap1, gcur2, cap2);
    k_fused1<<<nt1 + ng1, 512, 0, stream>>>(esrc, edst, part1, gcur1,
                                            E, sw1, magic1, cap1, nt1,
                                            x, Wt1, z1, r1, N);
    k_part2<<<392, 256, 0, stream>>>(part1, gcur1, part2, gcur2, cap1, cap2,
                                     sw2, magic2);
    k_agg1g2<<<1024, 512, 0, stream>>>(z1, r1, b1, part2, gcur2,
                                       Wt2, z2p, r2, rsg, N, sw1, sw2, cap2);
    k_agg2_f<<<1024, 512, 0, stream>>>(z2p, r2, b2, part2, gcur2, rsg, out,
                                       N, sw1, sw2, cap2);
}

// Round 18
// 183.093 us; speedup vs baseline: 1.0781x; 1.0781x over previous
//
#include <hip/hip_runtime.h>
#include <stdint.h>

// GraphSAGE 2-layer, MI355X. Round 18: revert to R15 config (183.8us best).
// R16's gemm2-into-agg1 fusion cut occupancy 69->45% (LDS 22.5->42.5KB) and
// slowed the latency-bound gather by more than the saved launch. Keep the
// proven separate kernels:
//   k_prep -> k_fused1 (part1 || gemm1) -> k_part2 (4096-tiles, CAPB=96) ->
//   k_agg1_f (counting-sort persisted + 16B/lane gather) -> k_gemm2 ->
//   k_agg2_f (pre-sorted gather + log_softmax)

typedef unsigned int uint32;
typedef unsigned short u16;
typedef __bf16 bf16x8 __attribute__((ext_vector_type(8)));
typedef float  f32x4  __attribute__((ext_vector_type(4)));
typedef unsigned short u16x8 __attribute__((ext_vector_type(8)));

#define CAPB 96     // part2 per-sub-bucket LDS staging (4096-edge tiles)
#define MAXE 2592   // agg LDS edge buffer (>= cap2)
#define MAXN 104    // agg max nodes per bucket
#define RSST 112    // rsg row stride (ints)

__device__ __forceinline__ float bf2f(u16 u) {
    union { uint32 i; float f; } v; v.i = ((uint32)u) << 16; return v.f;
}
__device__ __forceinline__ u16 f2bf(float f) {
    union { float f; uint32 i; } v; v.f = f;
    uint32 i = v.i;
    uint32 r = (i + 0x7FFFu + ((i >> 16) & 1u)) >> 16;  // RNE
    return (u16)r;
}

// ---------------- weight prep: transpose + bf16 + gcur inits ----------------
__global__ void k_prep(const float* __restrict__ W1l, const float* __restrict__ W1r,
                       const float* __restrict__ W2l, const float* __restrict__ W2r,
                       u16* __restrict__ Wt1, u16* __restrict__ Wt2,
                       int* __restrict__ gcur1, int cap1,
                       int* __restrict__ gcur2, int cap2) {
    if (blockIdx.x == 0 && threadIdx.x < 8) gcur1[threadIdx.x] = threadIdx.x * cap1;
    if (blockIdx.x < 4) {
        int idx = blockIdx.x * 256 + threadIdx.x;
        gcur2[idx] = idx * cap2;
    }
    if (blockIdx.x < 128) {
        int idx = blockIdx.x * 256 + threadIdx.x;
        int c = idx >> 7, k = idx & 127;
        float v = (c < 128) ? W1l[k * 128 + c] : W1r[k * 128 + (c - 128)];
        Wt1[idx] = f2bf(v);
    } else {
        int idx = (blockIdx.x - 128) * 256 + threadIdx.x;  // 96*128 total
        int c = idx >> 7, k = idx & 127;
        const float* W = (c < 48) ? W2l : W2r;
        int cc = (c < 48) ? c : c - 48;
        float v = (cc < 40) ? W[k * 40 + cc] : 0.f;
        Wt2[idx] = f2bf(v);
    }
}

// ---------------- fused: part1 (blocks < nt1) | gemm1 (blocks >= nt1) --------
__global__ __launch_bounds__(512) void k_fused1(
        const int* __restrict__ src, const int* __restrict__ dst,
        uint32* __restrict__ part, int* __restrict__ gcur,
        int E, int sw, uint32 magic, int cap, int nt1,
        const float* __restrict__ x, const u16* __restrict__ Wt,
        u16* __restrict__ z1, u16* __restrict__ r1, int N) {
    int tid = threadIdx.x;
    if ((int)blockIdx.x < nt1) {
        // ---------------- part1 tile ----------------
        __shared__ uint32 buf[2048];
        __shared__ int cnt8[8][8];
        __shared__ int base8[8][8];
        __shared__ int bstart[8], bn[8], gbase[8];
        int rep = tid & 7;
        int tile = blockIdx.x;
        if (tid < 64) cnt8[tid >> 3][tid & 7] = 0;
        __syncthreads();
        int e0 = (tile << 11) + tid * 4;
        int bk[4]; uint32 pk[4]; int nv = 0;
        if (e0 + 3 < E) {
            int4 d4 = *(const int4*)(dst + e0);
            int4 s4 = *(const int4*)(src + e0);
            int dd[4] = {d4.x, d4.y, d4.z, d4.w};
            int ss[4] = {s4.x, s4.y, s4.z, s4.w};
            nv = 4;
#pragma unroll
            for (int k = 0; k < 4; ++k) {
                bk[k] = (int)(((unsigned long long)(uint32)dd[k] * magic) >> 32);
                pk[k] = ((uint32)ss[k] << 14) | (uint32)(dd[k] - bk[k] * sw);
            }
        } else {
            for (int e = e0; e < E && e < e0 + 4; ++e) {
                int d = dst[e];
                int b = (int)(((unsigned long long)(uint32)d * magic) >> 32);
                bk[nv] = b;
                pk[nv] = ((uint32)src[e] << 14) | (uint32)(d - b * sw);
                ++nv;
            }
        }
        for (int k = 0; k < nv; ++k) atomicAdd(&cnt8[bk[k]][rep], 1);
        __syncthreads();
        if (tid == 0) {
            int run = 0;
            for (int b = 0; b < 8; ++b) {
                bstart[b] = run; int t0 = run;
                for (int r = 0; r < 8; ++r) { base8[b][r] = run; run += cnt8[b][r]; }
                bn[b] = run - t0;
            }
        }
        __syncthreads();
        if (tid < 64) cnt8[tid >> 3][tid & 7] = base8[tid >> 3][tid & 7];
        __syncthreads();
        for (int k = 0; k < nv; ++k) {
            int pos = atomicAdd(&cnt8[bk[k]][rep], 1);
            buf[pos] = pk[k];
        }
        if (tid < 8 && bn[tid] > 0)
            gbase[tid] = atomicAdd(&gcur[tid], bn[tid]);
        __syncthreads();
#pragma unroll
        for (int b = 0; b < 8; ++b) {
            int n = bn[b];
            if (n == 0) continue;
            int gb = gbase[b], bs = bstart[b];
            int lim = (b + 1) * cap;
            for (int i = tid; i < n; i += 512) {
                int p = gb + i;
                if (p < lim) part[p] = buf[bs + i];
            }
        }
    } else {
        // ---------------- gemm1 tile ----------------
        __shared__ u16 xs[128][136];
        int rbase = ((int)blockIdx.x - nt1) * 128;
#pragma unroll
        for (int i = 0; i < 8; ++i) {       // 4096 float4 chunks, coalesced
            int fi = tid + i * 512;
            int row = fi >> 5, c4 = fi & 31;
            int grow = rbase + row;
            grow = grow < N ? grow : N - 1;
            float4 v = *(const float4*)(x + ((size_t)grow << 7) + c4 * 4);
            ushort4 w4;
            w4.x = f2bf(v.x); w4.y = f2bf(v.y); w4.z = f2bf(v.z); w4.w = f2bf(v.w);
            *(ushort4*)&xs[row][c4 * 4] = w4;
        }

        int lane = tid & 63;
        int w    = tid >> 6;
        int l15 = lane & 15, g = lane >> 4;
        int rloc = (w >> 2) * 64;
        int cbase = (w & 3) * 64;

        bf16x8 Bf[4][4];
#pragma unroll
        for (int c = 0; c < 4; ++c)
#pragma unroll
            for (int ks = 0; ks < 4; ++ks)
                Bf[c][ks] = *(const bf16x8*)(Wt + (((size_t)(cbase + c * 16 + l15)) << 7)
                                                + ks * 32 + g * 8);

        f32x4 acc[4][4];
        f32x4 z4 = {0.f, 0.f, 0.f, 0.f};
#pragma unroll
        for (int r = 0; r < 4; ++r)
#pragma unroll
            for (int c = 0; c < 4; ++c) acc[r][c] = z4;

        __syncthreads();

#pragma unroll
        for (int ks = 0; ks < 4; ++ks) {
            bf16x8 Af[4];
#pragma unroll
            for (int r = 0; r < 4; ++r)
                Af[r] = *(const bf16x8*)&xs[rloc + r * 16 + l15][ks * 32 + g * 8];
#pragma unroll
            for (int r = 0; r < 4; ++r)
#pragma unroll
                for (int c = 0; c < 4; ++c)
                    acc[r][c] = __builtin_amdgcn_mfma_f32_16x16x32_bf16(
                                    Af[r], Bf[c][ks], acc[r][c], 0, 0, 0);
        }

        // C/D layout: col = lane&15, row = (lane>>4)*4 + j
#pragma unroll
        for (int r = 0; r < 4; ++r) {
#pragma unroll
            for (int c = 0; c < 4; ++c) {
                int col = cbase + c * 16 + l15;
                u16* out = (col < 128) ? z1 : r1;
                int cc = col & 127;
#pragma unroll
                for (int j = 0; j < 4; ++j) {
                    int row = rbase + rloc + r * 16 + g * 4 + j;
                    if (row < N) out[((size_t)row << 7) + cc] = f2bf(acc[r][c][j]);
                }
            }
        }
    }
}

// ---------------- pass 2: slice -> 128 sub-buckets (4096-edge tiles) ---------
__global__ __launch_bounds__(256) void k_part2(const uint32* __restrict__ part1,
        const int* __restrict__ gcur1, uint32* __restrict__ part2,
        int* __restrict__ gcur2, int cap1, int cap2, int sw2, uint32 magic2) {
    __shared__ uint32 buf[128][CAPB];
    __shared__ int lcnt[128], gbase[128];
    int s = blockIdx.x & 7;
    int m = gcur1[s] - s * cap1;
    const uint32* p1 = part1 + (size_t)s * cap1;
    int sbase = s * 128;
    int ntiles = (m + 4095) >> 12;
    for (int tile = blockIdx.x >> 3; tile < ntiles; tile += (gridDim.x >> 3)) {
        for (int i = threadIdx.x; i < 128; i += 256) lcnt[i] = 0;
        __syncthreads();
#pragma unroll
        for (int q = 0; q < 4; ++q) {
            int t0 = (tile << 12) + q * 1024 + threadIdx.x * 4;
            if (t0 + 3 < m) {
                uint4 v4 = *(const uint4*)(p1 + t0);
                uint32 vv[4] = {v4.x, v4.y, v4.z, v4.w};
#pragma unroll
                for (int k = 0; k < 4; ++k) {
                    uint32 dl = vv[k] & 16383u;
                    int sub = (int)(((unsigned long long)dl * magic2) >> 32);
                    uint32 pk = ((vv[k] >> 14) << 7) | (dl - (uint32)(sub * sw2));
                    int slot = atomicAdd(&lcnt[sub], 1);
                    if (slot < CAPB) buf[sub][slot] = pk;
                    else {   // rare spill: direct global append (no drops)
                        int p = atomicAdd(&gcur2[sbase + sub], 1);
                        if (p < (sbase + sub + 1) * cap2) part2[p] = pk;
                    }
                }
            } else {
                for (int idx = t0; idx < m && idx < t0 + 4; ++idx) {
                    uint32 v = p1[idx];
                    uint32 dl = v & 16383u;
                    int sub = (int)(((unsigned long long)dl * magic2) >> 32);
                    uint32 pk = ((v >> 14) << 7) | (dl - (uint32)(sub * sw2));
                    int slot = atomicAdd(&lcnt[sub], 1);
                    if (slot < CAPB) buf[sub][slot] = pk;
                    else {
                        int p = atomicAdd(&gcur2[sbase + sub], 1);
                        if (p < (sbase + sub + 1) * cap2) part2[p] = pk;
                    }
                }
            }
        }
        __syncthreads();
        if (threadIdx.x < 128) {
            int n = min(lcnt[threadIdx.x], CAPB);
            lcnt[threadIdx.x] = n;
            if (n > 0) gbase[threadIdx.x] = atomicAdd(&gcur2[sbase + threadIdx.x], n);
        }
        __syncthreads();
        int b = threadIdx.x >> 1, halfsel = threadIdx.x & 1;
        int n = lcnt[b];
        if (n > 0) {
            int gb = gbase[b];
            int lim = (sbase + b + 1) * cap2;
            for (int i = halfsel; i < n; i += 2) {
                int p = gb + i;
                if (p < lim) part2[p] = buf[b][i];
            }
        }
        __syncthreads();
    }
}

// ---------------- Layer-2 GEMM (MFMA, LDS-staged A): [n,128]bf16 x [128,96] --
__global__ __launch_bounds__(256) void k_gemm2(const u16* __restrict__ hb,
        const u16* __restrict__ Wt2,
        u16* __restrict__ z2p, u16* __restrict__ r2, int N) {
    __shared__ u16 hs[128][136];
    int tid = threadIdx.x;
    int rbase = blockIdx.x * 128;
#pragma unroll
    for (int i = 0; i < 8; ++i) {           // 2048 16B chunks, coalesced
        int ci = tid + i * 256;
        int row = ci >> 4, c8 = ci & 15;
        int grow = rbase + row;
        grow = grow < N ? grow : N - 1;
        u16x8 v = *(const u16x8*)(hb + ((size_t)grow << 7) + c8 * 8);
        *(u16x8*)&hs[row][c8 * 8] = v;
    }

    int lane = tid & 63;
    int w    = tid >> 6;          // 0..3
    int l15 = lane & 15, g = lane >> 4;
    int rloc = (w >> 1) * 64;
    int half = w & 1;

    bf16x8 Bf[3][4];
#pragma unroll
    for (int c = 0; c < 3; ++c)
#pragma unroll
        for (int ks = 0; ks < 4; ++ks)
            Bf[c][ks] = *(const bf16x8*)(Wt2 + (((size_t)(half * 48 + c * 16 + l15)) << 7)
                                             + ks * 32 + g * 8);

    f32x4 acc[4][3];
    f32x4 z4 = {0.f, 0.f, 0.f, 0.f};
#pragma unroll
    for (int r = 0; r < 4; ++r)
#pragma unroll
        for (int c = 0; c < 3; ++c) acc[r][c] = z4;

    __syncthreads();

#pragma unroll
    for (int ks = 0; ks < 4; ++ks) {
        bf16x8 Af[4];
#pragma unroll
        for (int r = 0; r < 4; ++r)
            Af[r] = *(const bf16x8*)&hs[rloc + r * 16 + l15][ks * 32 + g * 8];
#pragma unroll
        for (int r = 0; r < 4; ++r)
#pragma unroll
            for (int c = 0; c < 3; ++c)
                acc[r][c] = __builtin_amdgcn_mfma_f32_16x16x32_bf16(
                                Af[r], Bf[c][ks], acc[r][c], 0, 0, 0);
    }

    if (half == 0) {
#pragma unroll
        for (int r = 0; r < 4; ++r)
#pragma unroll
            for (int c = 0; c < 3; ++c) {
                int col = c * 16 + l15;
#pragma unroll
                for (int j = 0; j < 4; ++j) {
                    int row = rbase + rloc + r * 16 + g * 4 + j;
                    if (row < N) z2p[((size_t)row << 6) + col] = f2bf(acc[r][c][j]);
                }
            }
        int row = rbase + rloc + lane;  // zero-fill cols 48..63 (wave's 64 rows)
        if (row < N) {
            u16x8 z8 = {0, 0, 0, 0, 0, 0, 0, 0};
            *(u16x8*)(z2p + ((size_t)row << 6) + 48) = z8;
            *(u16x8*)(z2p + ((size_t)row << 6) + 56) = z8;
        }
    } else {
#pragma unroll
        for (int r = 0; r < 4; ++r)
#pragma unroll
            for (int c = 0; c < 3; ++c) {
                int col = c * 16 + l15;
                if (col < 40) {
#pragma unroll
                    for (int j = 0; j < 4; ++j) {
                        int row = rbase + rloc + r * 16 + g * 4 + j;
                        if (row < N) r2[(size_t)row * 40 + col] = f2bf(acc[r][c][j]);
                    }
                }
            }
    }
}

// ---------------- Layer-1 agg: counting-sort (persisted) + wide gather -------
__global__ __launch_bounds__(512) void k_agg1_f(const u16* __restrict__ z1,
        const u16* __restrict__ r1, const float* __restrict__ b1,
        uint32* __restrict__ part2, const int* __restrict__ gcur2,
        u16* __restrict__ h, int* __restrict__ rsg,
        int N, int sw1, int sw2, int cap2) {
    __shared__ uint32 ebuf[MAXE];
    __shared__ uint32 esrt[MAXE];
    __shared__ int cnt[MAXN], cur[MAXN], rs[MAXN + 32];
    int b = blockIdx.x, s = b >> 7, sub = b & 127;
    int nb = s * sw1 + sub * sw2;
    int slice_end = min((s + 1) * sw1, N);
    int nn = min(sw2, slice_end - nb);
    if (nn <= 0) return;
    int tid = threadIdx.x;
    int m2 = gcur2[b] - b * cap2;
    m2 = min(m2, min(cap2, MAXE));
    uint32* p2 = part2 + (size_t)b * cap2;

    for (int i = tid; i < m2; i += 512) ebuf[i] = p2[i];
    for (int i = tid; i < nn; i += 512) cnt[i] = 0;
    __syncthreads();
    for (int i = tid; i < m2; i += 512) atomicAdd(&cnt[ebuf[i] & 127], 1);
    __syncthreads();
    if (tid < 64) {   // wave-0 prefix scan of cnt[0..103] -> rs (exclusive)
        int c0 = (tid < nn) ? cnt[tid] : 0;
        int c1 = (64 + tid < nn) ? cnt[64 + tid] : 0;
        for (int off = 1; off < 64; off <<= 1) {
            int t0 = __shfl_up(c0, off, 64);
            int t1 = __shfl_up(c1, off, 64);
            if (tid >= off) { c0 += t0; c1 += t1; }
        }
        int tot0 = __shfl(c0, 63, 64);
        if (tid == 0) rs[0] = 0;
        rs[tid + 1] = c0;
        rs[64 + tid + 1] = tot0 + c1;
    }
    __syncthreads();
    for (int i = tid; i < nn; i += 512) cur[i] = rs[i];
    __syncthreads();
    for (int i = tid; i < m2; i += 512) {   // place srcs sorted by dst
        uint32 v = ebuf[i];
        int pos = atomicAdd(&cur[v & 127], 1);
        esrt[pos] = v >> 7;
    }
    __syncthreads();

    // persist sorted list + rowstarts for k_agg2_f (coalesced)
    for (int i = tid; i < m2; i += 512) p2[i] = esrt[i];
    for (int i = tid; i <= nn; i += 512) rsg[b * RSST + i] = rs[i];

    int lane = tid & 63, wv = tid >> 6;
    int g = lane >> 4, c = lane & 15;
    for (int node = wv; node < nn; node += 8) {
        int s0 = rs[node], s1 = rs[node + 1];
        float acc[8];
#pragma unroll
        for (int i = 0; i < 8; ++i) acc[i] = 0.f;
        int j = s0 + g;
        for (; j + 12 < s1; j += 16) {
            int sA = esrt[j], sB = esrt[j + 4];
            int sC = esrt[j + 8], sD = esrt[j + 12];
            u16x8 a = *(const u16x8*)(z1 + ((size_t)sA << 7) + c * 8);
            u16x8 bb = *(const u16x8*)(z1 + ((size_t)sB << 7) + c * 8);
            u16x8 d = *(const u16x8*)(z1 + ((size_t)sC << 7) + c * 8);
            u16x8 e = *(const u16x8*)(z1 + ((size_t)sD << 7) + c * 8);
#pragma unroll
            for (int i = 0; i < 8; ++i)
                acc[i] += (bf2f(a[i]) + bf2f(bb[i])) + (bf2f(d[i]) + bf2f(e[i]));
        }
        for (; j + 4 < s1; j += 8) {
            int sA = esrt[j], sB = esrt[j + 4];
            u16x8 a = *(const u16x8*)(z1 + ((size_t)sA << 7) + c * 8);
            u16x8 bb = *(const u16x8*)(z1 + ((size_t)sB << 7) + c * 8);
#pragma unroll
            for (int i = 0; i < 8; ++i) acc[i] += bf2f(a[i]) + bf2f(bb[i]);
        }
        if (j < s1) {
            int sA = esrt[j];
            u16x8 a = *(const u16x8*)(z1 + ((size_t)sA << 7) + c * 8);
#pragma unroll
            for (int i = 0; i < 8; ++i) acc[i] += bf2f(a[i]);
        }
#pragma unroll
        for (int i = 0; i < 8; ++i) {
            acc[i] += __shfl_xor(acc[i], 16, 64);
            acc[i] += __shfl_xor(acc[i], 32, 64);
        }
        if (g == 0) {
            float inv = 1.0f / fmaxf((float)(s1 - s0), 1.0f);
            size_t go = ((size_t)(nb + node) << 7) + c * 8;
            u16x8 rv = *(const u16x8*)(r1 + go);
            float4 b0 = *(const float4*)(b1 + c * 8);
            float4 b4 = *(const float4*)(b1 + c * 8 + 4);
            float bbv[8] = {b0.x, b0.y, b0.z, b0.w, b4.x, b4.y, b4.z, b4.w};
            u16x8 o;
#pragma unroll
            for (int i = 0; i < 8; ++i)
                o[i] = f2bf(fmaxf(acc[i] * inv + bf2f(rv[i]) + bbv[i], 0.f));
            *(u16x8*)(h + go) = o;
        }
    }
}

// ---------------- Layer-2 agg: pre-sorted gather + log_softmax ---------------
__global__ __launch_bounds__(512) void k_agg2_f(const u16* __restrict__ z2p,
        const u16* __restrict__ r2, const float* __restrict__ b2,
        const uint32* __restrict__ part2, const int* __restrict__ gcur2,
        const int* __restrict__ rsg, float* __restrict__ out,
        int N, int sw1, int sw2, int cap2) {
    __shared__ uint32 esrt[MAXE];
    __shared__ int rs[MAXN + 1];
    int b = blockIdx.x, s = b >> 7, sub = b & 127;
    int nb = s * sw1 + sub * sw2;
    int slice_end = min((s + 1) * sw1, N);
    int nn = min(sw2, slice_end - nb);
    if (nn <= 0) return;
    int tid = threadIdx.x;
    int m2 = gcur2[b] - b * cap2;
    m2 = min(m2, min(cap2, MAXE));
    const uint32* p2 = part2 + (size_t)b * cap2;

    for (int i = tid; i < m2; i += 512) esrt[i] = p2[i];
    for (int i = tid; i <= nn; i += 512) rs[i] = rsg[b * RSST + i];
    __syncthreads();

    int lane = tid & 63, wv = tid >> 6;
    int le = lane >> 3, c = lane & 7;
    bool act = c < 5;
    for (int node = wv; node < nn; node += 8) {
        int s0 = rs[node], s1 = rs[node + 1];
        float acc[8];
#pragma unroll
        for (int i = 0; i < 8; ++i) acc[i] = 0.f;
        int j = s0 + le;
        for (; j + 8 < s1; j += 16) {
            int sA = esrt[j], sB = esrt[j + 8];
            u16x8 a = *(const u16x8*)(z2p + ((size_t)sA << 6) + c * 8);
            u16x8 bb = *(const u16x8*)(z2p + ((size_t)sB << 6) + c * 8);
#pragma unroll
            for (int i = 0; i < 8; ++i) acc[i] += bf2f(a[i]) + bf2f(bb[i]);
        }
        if (j < s1) {
            int sA = esrt[j];
            u16x8 a = *(const u16x8*)(z2p + ((size_t)sA << 6) + c * 8);
#pragma unroll
            for (int i = 0; i < 8; ++i) acc[i] += bf2f(a[i]);
        }
#pragma unroll
        for (int i = 0; i < 8; ++i) {
            acc[i] += __shfl_xor(acc[i], 8, 64);
            acc[i] += __shfl_xor(acc[i], 16, 64);
            acc[i] += __shfl_xor(acc[i], 32, 64);
        }
        if (le == 0) {   // lanes 0..7: chans c*8..c*8+7; only c<5 real (40 ch)
            float inv = 1.0f / fmaxf((float)(s1 - s0), 1.0f);
            float v[8];
            if (act) {
                u16x8 rv = *(const u16x8*)(r2 + (size_t)(nb + node) * 40 + c * 8);
                float4 b0 = *(const float4*)(b2 + c * 8);
                float4 b4 = *(const float4*)(b2 + c * 8 + 4);
                float bbv[8] = {b0.x, b0.y, b0.z, b0.w, b4.x, b4.y, b4.z, b4.w};
#pragma unroll
                for (int i = 0; i < 8; ++i) v[i] = acc[i] * inv + bf2f(rv[i]) + bbv[i];
            } else {
#pragma unroll
                for (int i = 0; i < 8; ++i) v[i] = -1e30f;
            }
            float m = v[0];
#pragma unroll
            for (int i = 1; i < 8; ++i) m = fmaxf(m, v[i]);
            m = fmaxf(m, __shfl_xor(m, 1, 64));
            m = fmaxf(m, __shfl_xor(m, 2, 64));
            m = fmaxf(m, __shfl_xor(m, 4, 64));
            float sum = 0.f;
            if (act) {
#pragma unroll
                for (int i = 0; i < 8; ++i) sum += __expf(v[i] - m);
            }
            sum += __shfl_xor(sum, 1, 64);
            sum += __shfl_xor(sum, 2, 64);
            sum += __shfl_xor(sum, 4, 64);
            float lse = __logf(sum);
            if (act) {
                float4 o0, o4;
                o0.x = v[0] - m - lse; o0.y = v[1] - m - lse;
                o0.z = v[2] - m - lse; o0.w = v[3] - m - lse;
                o4.x = v[4] - m - lse; o4.y = v[5] - m - lse;
                o4.z = v[6] - m - lse; o4.w = v[7] - m - lse;
                *(float4*)(out + (size_t)(nb + node) * 40 + c * 8) = o0;
                *(float4*)(out + (size_t)(nb + node) * 40 + c * 8 + 4) = o4;
            }
        }
    }
}

extern "C" void kernel_launch(void* const* d_in, const int* in_sizes, int n_in,
                              void* d_out, int out_size, void* d_ws, size_t ws_size,
                              hipStream_t stream) {
    const float* x   = (const float*)d_in[0];
    const int*   ei  = (const int*)d_in[1];   // [2][E] int32
    const float* W1l = (const float*)d_in[2];
    const float* W1r = (const float*)d_in[3];
    const float* b1  = (const float*)d_in[4];
    const float* W2l = (const float*)d_in[5];
    const float* W2r = (const float*)d_in[6];
    const float* b2  = (const float*)d_in[7];
    float* out = (float*)d_out;

    int N = in_sizes[0] / 128;
    int E = in_sizes[1] / 2;
    const int* esrc = ei;
    const int* edst = ei + E;

    int sw1 = (N + 7) / 8;                               // 12500 (<=16384: 14 bits)
    int sw2 = (sw1 + 127) / 128;                         // 98 (<=104: LDS bound)
    uint32 magic1 = (uint32)((((unsigned long long)1 << 32) + sw1 - 1) / sw1);
    uint32 magic2 = (uint32)((((unsigned long long)1 << 32) + sw2 - 1) / sw2);
    int cap1 = (((E >> 3) + 8192) + 3) & ~3;
    int cap2 = (((E >> 10) + 1024) + 3) & ~3;            // 2588 <= MAXE

    // workspace carve (256B aligned)
    char* p = (char*)d_ws;
    size_t off = 0;
    auto alloc = [&](size_t bytes) {
        void* q = p + off;
        off = (off + bytes + 255) & ~(size_t)255;
        return q;
    };
    int* gcur1 = (int*)alloc(64);
    int* gcur2 = (int*)alloc(1024 * 4);
    int* rsg   = (int*)alloc((size_t)1024 * RSST * 4);
    u16* Wt1 = (u16*)alloc(256 * 128 * 2);
    u16* Wt2 = (u16*)alloc(96 * 128 * 2);
    uint32* part1 = (uint32*)alloc((size_t)8 * cap1 * 4);
    uint32* part2 = (uint32*)alloc((size_t)1024 * cap2 * 4);
    u16* z1 = (u16*)alloc((size_t)N * 128 * 2);
    u16* r1 = (u16*)alloc((size_t)N * 128 * 2);
    u16* hb = r1;                         // h aliases r1 (elementwise)
    // layer-2 buffers reuse z1 (dead after agg1): z2p bf16 N*64, r2 after it
    u16* z2p = z1;
    u16* r2  = z1 + (size_t)N * 64;

    int nt1 = (E + 2047) >> 11;           // part1 tiles (2048 edges, 512 thr)
    int ng1 = (N + 127) / 128;            // gemm1 tiles

    k_prep<<<176, 256, 0, stream>>>(W1l, W1r, W2l, W2r, Wt1, Wt2,
                                    gcur1, cap1, gcur2, cap2);
    k_fused1<<<nt1 + ng1, 512, 0, stream>>>(esrc, edst, part1, gcur1,
                                            E, sw1, magic1, cap1, nt1,
                                            x, Wt1, z1, r1, N);
    k_part2<<<392, 256, 0, stream>>>(part1, gcur1, part2, gcur2, cap1, cap2,
                                     sw2, magic2);
    k_agg1_f<<<1024, 512, 0, stream>>>(z1, r1, b1, part2, gcur2, hb, rsg,
                                       N, sw1, sw2, cap2);
    k_gemm2<<<(N + 127) / 128, 256, 0, stream>>>(hb, Wt2, z2p, r2, N);
    k_agg2_f<<<1024, 512, 0, stream>>>(z2p, r2, b2, part2, gcur2, rsg, out,
                                       N, sw1, sw2, cap2);
}